// Round 5
// baseline (62.732 us; speedup 1.0000x reference)
//
#include <hip/hip_runtime.h>

typedef float v2f __attribute__((ext_vector_type(2)));

#define KS 7
#define NG 16
#define PAD 3
#define NB 4
#define NC 64
#define NH 128
#define NW 128
#define HW (NH*NW)
#define NR 16
#define CG 4            // NC/NG
#define TW 8            // tile width
#define TH 16           // tile height (each lane: 2 pixels, rows ph and ph+8)
#define HWT 14          // TW + 2*PAD
#define HHT 22          // TH + 2*PAD
#define KK 49           // KS*KS
#define WPB 4           // waves (= groups) per block

// ---------------- Kernel A: red[b][pix][r] = relu(w_reduce @ x + b_reduce) ----
__global__ __launch_bounds__(256)
void red_kernel(const float* __restrict__ x,
                const float* __restrict__ w_reduce,
                const float* __restrict__ b_reduce,
                float* __restrict__ red) {
    __shared__ float wT[NC][NR];           // transposed: wT[c][r]
    const int t = threadIdx.x;
    #pragma unroll
    for (int e = 0; e < 4; ++e) {
        int i = t * 4 + e;                 // 0..1023, coalesced
        wT[i & 63][i >> 6] = w_reduce[i];  // w_reduce[r*64+c] -> wT[c][r]
    }
    __syncthreads();

    const int p   = blockIdx.x * 256 + t;  // 0..65535
    const int b   = p >> 14;               // /16384
    const int pix = p & 16383;

    float acc[NR];
    #pragma unroll
    for (int r = 0; r < NR; ++r) acc[r] = b_reduce[r];

    const float* xp = x + (size_t)b * (NC * HW) + pix;
    #pragma unroll 16
    for (int c = 0; c < NC; ++c) {
        float xv = xp[(size_t)c * HW];     // coalesced across lanes
        const float4* wv = (const float4*)&wT[c][0];     // broadcast reads
        float4 w0 = wv[0], w1 = wv[1], w2 = wv[2], w3 = wv[3];
        acc[0]  = fmaf(w0.x, xv, acc[0]);  acc[1]  = fmaf(w0.y, xv, acc[1]);
        acc[2]  = fmaf(w0.z, xv, acc[2]);  acc[3]  = fmaf(w0.w, xv, acc[3]);
        acc[4]  = fmaf(w1.x, xv, acc[4]);  acc[5]  = fmaf(w1.y, xv, acc[5]);
        acc[6]  = fmaf(w1.z, xv, acc[6]);  acc[7]  = fmaf(w1.w, xv, acc[7]);
        acc[8]  = fmaf(w2.x, xv, acc[8]);  acc[9]  = fmaf(w2.y, xv, acc[9]);
        acc[10] = fmaf(w2.z, xv, acc[10]); acc[11] = fmaf(w2.w, xv, acc[11]);
        acc[12] = fmaf(w3.x, xv, acc[12]); acc[13] = fmaf(w3.y, xv, acc[13]);
        acc[14] = fmaf(w3.z, xv, acc[14]); acc[15] = fmaf(w3.w, xv, acc[15]);
    }
    #pragma unroll
    for (int r = 0; r < NR; ++r) acc[r] = fmaxf(acc[r], 0.f);

    float4* rp = (float4*)(red + (size_t)p * NR);        // 64B/lane, coalesced
    rp[0] = make_float4(acc[0],  acc[1],  acc[2],  acc[3]);
    rp[1] = make_float4(acc[4],  acc[5],  acc[6],  acc[7]);
    rp[2] = make_float4(acc[8],  acc[9],  acc[10], acc[11]);
    rp[3] = make_float4(acc[12], acc[13], acc[14], acc[15]);
}

// ---------------- Kernel B: fused span->exp->gather, 2 pixels per lane --------
// 256-thread blocks = 4 waves; wave wv = group blockIdx.y*4+wv on an 8x16 tile.
// Each lane owns pixels (ph,pw) and (ph+8,pw): one w_span scalar-load stream
// serves both pixels; span math packed into v2f (pixel-pair) for v_pk_fma_f32.
__global__ __launch_bounds__(256, 4)
void invol_kernel(const float* __restrict__ x,
                  const float* __restrict__ w_span,
                  const float* __restrict__ b_span,
                  const float* __restrict__ red,
                  float* __restrict__ out) {
    __shared__ float4 xs[WPB][HHT][HWT];   // 4 * 22 * 14 * 16B = 19712 B

    const int t    = threadIdx.x;
    const int lane = t & 63;
    const int wv   = __builtin_amdgcn_readfirstlane(t >> 6);   // 0..3, SGPR
    const int ph = lane >> 3, pw = lane & 7;
    const int h0 = (blockIdx.x >> 4) * TH;     // blockIdx.x 0..127 -> th 0..7
    const int w0 = (blockIdx.x & 15) * TW;
    const int g  = blockIdx.y * WPB + wv;      // SGPR
    const int b  = blockIdx.z;

    // ---- stage 22x14 float4 halo (4 group-channels per position) ----
    const float* xb = x + (size_t)(b * NC + g * CG) * HW;
    #pragma unroll
    for (int it = 0; it < 5; ++it) {
        int idx = lane + it * 64;              // 0..319, need < 308
        if (idx < HHT * HWT) {
            int hh = idx / HWT;
            int ww = idx - hh * HWT;
            int gh = h0 + hh - PAD;
            int gw = w0 + ww - PAD;
            float4 v = make_float4(0.f, 0.f, 0.f, 0.f);
            if ((unsigned)gh < NH && (unsigned)gw < NW) {
                const float* p = xb + gh * NW + gw;
                v.x = p[0];
                v.y = p[HW];
                v.z = p[2 * HW];
                v.w = p[3 * HW];
            }
            xs[wv][hh][ww] = v;
        }
    }
    __syncthreads();

    // ---- reduced features for both pixels, packed pixel-pair into v2f ----
    const int pix1 = (h0 + ph) * NW + (w0 + pw);
    const int pix2 = pix1 + 8 * NW;
    const float4* rp1 = (const float4*)(red + ((size_t)b * HW + pix1) * NR);
    const float4* rp2 = (const float4*)(red + ((size_t)b * HW + pix2) * NR);
    v2f rv[NR];
    #pragma unroll
    for (int q = 0; q < 4; ++q) {
        float4 u1 = rp1[q], u2 = rp2[q];
        rv[q * 4 + 0] = (v2f){u1.x, u2.x};
        rv[q * 4 + 1] = (v2f){u1.y, u2.y};
        rv[q * 4 + 2] = (v2f){u1.z, u2.z};
        rv[q * 4 + 3] = (v2f){u1.w, u2.w};
    }

    const float* wg = w_span + (size_t)g * (KK * NR);   // scalar loads (g SGPR)
    const float* bg = b_span + (size_t)g * KK;

    // ---- fused per-tap: packed logit-pair -> exp -> weighted gather ----
    v2f esum = {0.f, 0.f};
    float a10 = 0.f, a11 = 0.f, a12 = 0.f, a13 = 0.f;
    float a20 = 0.f, a21 = 0.f, a22 = 0.f, a23 = 0.f;
    #pragma unroll
    for (int i = 0; i < KS; ++i) {
        #pragma unroll
        for (int j = 0; j < KS; ++j) {
            const int k = i * KS + j;
            const float* wk = wg + k * NR;
            const float bk = bg[k];
            v2f p0 = {bk, bk}, p1 = {0.f, 0.f}, p2 = {0.f, 0.f}, p3 = {0.f, 0.f};
            #pragma unroll
            for (int r = 0; r < NR; r += 4) {
                p0 += rv[r + 0] * wk[r + 0];   // scalar splat -> pk_fma (contract)
                p1 += rv[r + 1] * wk[r + 1];
                p2 += rv[r + 2] * wk[r + 2];
                p3 += rv[r + 3] * wk[r + 3];
            }
            v2f pl = (p0 + p1) + (p2 + p3);
            float e1 = __expf(pl.x);           // logits O(1): no max-sub
            float e2 = __expf(pl.y);
            esum += (v2f){e1, e2};
            float4 v1 = xs[wv][ph + i][pw + j];        // imm offset (i*14+j)*16
            float4 v2 = xs[wv][ph + 8 + i][pw + j];    // imm offset +1792
            a10 = fmaf(e1, v1.x, a10); a11 = fmaf(e1, v1.y, a11);
            a12 = fmaf(e1, v1.z, a12); a13 = fmaf(e1, v1.w, a13);
            a20 = fmaf(e2, v2.x, a20); a21 = fmaf(e2, v2.y, a21);
            a22 = fmaf(e2, v2.z, a22); a23 = fmaf(e2, v2.w, a23);
        }
    }
    float inv1 = 1.0f / esum.x;
    float inv2 = 1.0f / esum.y;

    const int h1 = h0 + ph, w = w0 + pw;
    size_t ob1 = ((size_t)(b * NC + g * CG) * NH + h1) * NW + w;
    size_t ob2 = ob1 + 8 * NW;
    out[ob1]          = a10 * inv1;
    out[ob1 + HW]     = a11 * inv1;
    out[ob1 + 2 * HW] = a12 * inv1;
    out[ob1 + 3 * HW] = a13 * inv1;
    out[ob2]          = a20 * inv2;
    out[ob2 + HW]     = a21 * inv2;
    out[ob2 + 2 * HW] = a22 * inv2;
    out[ob2 + 3 * HW] = a23 * inv2;
}

extern "C" void kernel_launch(void* const* d_in, const int* in_sizes, int n_in,
                              void* d_out, int out_size, void* d_ws, size_t ws_size,
                              hipStream_t stream) {
    const float* x        = (const float*)d_in[0];
    const float* w_reduce = (const float*)d_in[1];
    const float* b_reduce = (const float*)d_in[2];
    const float* w_span   = (const float*)d_in[3];
    const float* b_span   = (const float*)d_in[4];
    float* out = (float*)d_out;
    float* red = (float*)d_ws;               // 4 MB (B*H*W*16 fp32)

    red_kernel<<<dim3(NB * HW / 256), 256, 0, stream>>>(x, w_reduce, b_reduce, red);

    dim3 gridB(128, NG / WPB, NB);           // (8x16 tiles, group-quads, batch)
    invol_kernel<<<gridB, 256, 0, stream>>>(x, w_span, b_span, red, out);
}

// Round 6
// 57.378 us; speedup vs baseline: 1.0933x; 1.0933x over previous
//
#include <hip/hip_runtime.h>

typedef float v2f __attribute__((ext_vector_type(2)));

#define KS 7
#define NG 16
#define PAD 3
#define NB 4
#define NC 64
#define NH 128
#define NW 128
#define HW (NH*NW)
#define NR 16
#define CG 4            // NC/NG
#define KK 49           // KS*KS

#define BTH 16          // block tile rows
#define BTW 32          // block tile cols
#define HTH 22          // BTH + 2*PAD
#define HTW 38          // BTW + 2*PAD
#define WPB 4           // waves per block (4 column slices of the tile)

// ---------------- Kernel A: red[b][pix][r] = relu(w_reduce @ x + b_reduce) ----
// r-split 4-way: blockIdx.y = rq, each thread computes 4 of the 16 r outputs
// for one pixel -> 4096 waves (4/SIMD) instead of 1024 (1/SIMD).
__global__ __launch_bounds__(256)
void red_kernel(const float* __restrict__ x,
                const float* __restrict__ w_reduce,
                const float* __restrict__ b_reduce,
                float* __restrict__ red) {
    __shared__ float wT[NC][4];            // this rq's 4 rows, transposed
    const int t  = threadIdx.x;
    const int rq = blockIdx.y;             // 0..3
    {
        int e = t >> 6, c = t & 63;        // 256 threads cover 64x4
        wT[c][e] = w_reduce[(rq * 4 + e) * NC + c];
    }
    __syncthreads();

    const int p   = blockIdx.x * 256 + t;  // 0..65535
    const int b   = p >> 14;
    const int pix = p & 16383;

    float a0 = b_reduce[rq * 4 + 0];
    float a1 = b_reduce[rq * 4 + 1];
    float a2 = b_reduce[rq * 4 + 2];
    float a3 = b_reduce[rq * 4 + 3];

    const float* xp = x + (size_t)b * (NC * HW) + pix;
    #pragma unroll 16
    for (int c = 0; c < NC; ++c) {
        float xv = xp[(size_t)c * HW];     // coalesced across lanes
        float4 ww = *(const float4*)&wT[c][0];   // broadcast
        a0 = fmaf(ww.x, xv, a0);
        a1 = fmaf(ww.y, xv, a1);
        a2 = fmaf(ww.z, xv, a2);
        a3 = fmaf(ww.w, xv, a3);
    }
    float4 o = make_float4(fmaxf(a0, 0.f), fmaxf(a1, 0.f),
                           fmaxf(a2, 0.f), fmaxf(a3, 0.f));
    *(float4*)(red + (size_t)p * NR + rq * 4) = o;
}

// ---------------- Kernel B: fused span->exp->gather, weights in LDS -----------
// Block = one group, 16x32 pixel tile, 4 waves each owning an 8-col slice
// (2 pixels per lane: rows ph and ph+8). ALL hot-loop memory is DS (LDS):
// no SMEM in the loop -> in-order lgkmcnt -> taps software-pipeline.
__global__ __launch_bounds__(256, 4)
void invol_kernel(const float* __restrict__ x,
                  const float* __restrict__ w_span,
                  const float* __restrict__ b_span,
                  const float* __restrict__ red,
                  float* __restrict__ out) {
    __shared__ float4 xs[HTH * HTW];       // 836 * 16B = 13376 B
    __shared__ float  wls[KK * NR];        // 3136 B
    __shared__ float  bls[KK];             // 196 B

    const int t    = threadIdx.x;
    const int lane = t & 63;
    const int wv   = __builtin_amdgcn_readfirstlane(t >> 6);   // 0..3
    const int ph = lane >> 3, pw = lane & 7;
    const int h0 = (blockIdx.x >> 2) * BTH;    // 8 tile-rows
    const int w0 = (blockIdx.x & 3) * BTW;     // 4 tile-cols
    const int g  = blockIdx.y;
    const int b  = blockIdx.z;

    // ---- stage weights + bias for this group into LDS ----
    {
        const float4* wg4 = (const float4*)(w_span + (size_t)g * (KK * NR));
        if (t < KK * NR / 4) ((float4*)wls)[t] = wg4[t];       // 196 float4
        if (t >= 192 && t < 192 + KK) bls[t - 192] = b_span[g * KK + (t - 192)];
    }

    // ---- stage 22x38 float4 halo (4 group-channels per position) ----
    const float* xb = x + (size_t)(b * NC + g * CG) * HW;
    #pragma unroll
    for (int it = 0; it < 4; ++it) {
        int idx = t + it * 256;            // need < 836
        if (idx < HTH * HTW) {
            int hh = idx / HTW;
            int ww = idx - hh * HTW;
            int gh = h0 + hh - PAD;
            int gw = w0 + ww - PAD;
            float4 v = make_float4(0.f, 0.f, 0.f, 0.f);
            if ((unsigned)gh < NH && (unsigned)gw < NW) {
                const float* p = xb + gh * NW + gw;
                v.x = p[0];
                v.y = p[HW];
                v.z = p[2 * HW];
                v.w = p[3 * HW];
            }
            xs[idx] = v;
        }
    }
    __syncthreads();

    // ---- reduced features for both pixels, packed pixel-pair into v2f ----
    const int col  = wv * 8 + pw;          // 0..31
    const int pix1 = (h0 + ph) * NW + (w0 + col);
    const float4* rp1 = (const float4*)(red + ((size_t)b * HW + pix1) * NR);
    const float4* rp2 = (const float4*)(red + ((size_t)b * HW + pix1 + 8 * NW) * NR);
    v2f rv[NR];
    #pragma unroll
    for (int q = 0; q < 4; ++q) {
        float4 u1 = rp1[q], u2 = rp2[q];
        rv[q * 4 + 0] = (v2f){u1.x, u2.x};
        rv[q * 4 + 1] = (v2f){u1.y, u2.y};
        rv[q * 4 + 2] = (v2f){u1.z, u2.z};
        rv[q * 4 + 3] = (v2f){u1.w, u2.w};
    }

    // ---- fused per-tap: logit-pair -> exp -> weighted gather (all-DS loop) ----
    const int lb = ph * HTW + col;         // lane's base position in xs
    v2f esum = {0.f, 0.f};
    float a10 = 0.f, a11 = 0.f, a12 = 0.f, a13 = 0.f;
    float a20 = 0.f, a21 = 0.f, a22 = 0.f, a23 = 0.f;
    #pragma unroll
    for (int i = 0; i < KS; ++i) {
        #pragma unroll
        for (int j = 0; j < KS; ++j) {
            const int k = i * KS + j;
            const float4* wt = (const float4*)(wls + k * NR);  // uniform -> broadcast
            float4 wa = wt[0], wb_ = wt[1], wc = wt[2], wd = wt[3];
            float bk = bls[k];
            v2f p0 = {0.f, 0.f}, p1 = {0.f, 0.f}, p2 = {0.f, 0.f}, p3 = {0.f, 0.f};
            p0 += rv[0]  * wa.x;  p1 += rv[1]  * wa.y;
            p2 += rv[2]  * wa.z;  p3 += rv[3]  * wa.w;
            p0 += rv[4]  * wb_.x; p1 += rv[5]  * wb_.y;
            p2 += rv[6]  * wb_.z; p3 += rv[7]  * wb_.w;
            p0 += rv[8]  * wc.x;  p1 += rv[9]  * wc.y;
            p2 += rv[10] * wc.z;  p3 += rv[11] * wc.w;
            p0 += rv[12] * wd.x;  p1 += rv[13] * wd.y;
            p2 += rv[14] * wd.z;  p3 += rv[15] * wd.w;
            v2f pl = (p0 + p1) + (p2 + p3);
            float e1 = __expf(pl.x + bk);  // logits O(1): no max-sub needed
            float e2 = __expf(pl.y + bk);
            esum += (v2f){e1, e2};
            float4 v1 = xs[lb + i * HTW + j];              // imm offsets
            float4 v2 = xs[lb + (8 + i) * HTW + j];
            a10 = fmaf(e1, v1.x, a10); a11 = fmaf(e1, v1.y, a11);
            a12 = fmaf(e1, v1.z, a12); a13 = fmaf(e1, v1.w, a13);
            a20 = fmaf(e2, v2.x, a20); a21 = fmaf(e2, v2.y, a21);
            a22 = fmaf(e2, v2.z, a22); a23 = fmaf(e2, v2.w, a23);
        }
    }
    float inv1 = 1.0f / esum.x;
    float inv2 = 1.0f / esum.y;

    const int h1 = h0 + ph, w = w0 + col;
    size_t ob1 = ((size_t)(b * NC + g * CG) * NH + h1) * NW + w;
    size_t ob2 = ob1 + 8 * NW;
    out[ob1]          = a10 * inv1;
    out[ob1 + HW]     = a11 * inv1;
    out[ob1 + 2 * HW] = a12 * inv1;
    out[ob1 + 3 * HW] = a13 * inv1;
    out[ob2]          = a20 * inv2;
    out[ob2 + HW]     = a21 * inv2;
    out[ob2 + 2 * HW] = a22 * inv2;
    out[ob2 + 3 * HW] = a23 * inv2;
}

extern "C" void kernel_launch(void* const* d_in, const int* in_sizes, int n_in,
                              void* d_out, int out_size, void* d_ws, size_t ws_size,
                              hipStream_t stream) {
    const float* x        = (const float*)d_in[0];
    const float* w_reduce = (const float*)d_in[1];
    const float* b_reduce = (const float*)d_in[2];
    const float* w_span   = (const float*)d_in[3];
    const float* b_span   = (const float*)d_in[4];
    float* out = (float*)d_out;
    float* red = (float*)d_ws;               // 4 MB (B*H*W*16 fp32)

    red_kernel<<<dim3(NB * HW / 256, 4), 256, 0, stream>>>(x, w_reduce, b_reduce, red);

    dim3 gridB(32, NG, NB);                  // (16x32 tiles, groups, batch) = 2048
    invol_kernel<<<gridB, 256, 0, stream>>>(x, w_span, b_span, red, out);
}